// Round 3
// baseline (2581.423 us; speedup 1.0000x reference)
//
#include <hip/hip_runtime.h>
#include <hip/hip_bf16.h>
#include <cstdint>
#include <cstddef>

typedef unsigned short u16;
typedef __bf16 bf16x8 __attribute__((ext_vector_type(8)));
typedef float f32x4 __attribute__((ext_vector_type(4)));

#define LSTRIDE 40  // 64-row LDS tiles padded: 80B row stride -> 2-way bank aliasing (free)

static __device__ inline u16 f2bf(float f) {
    __hip_bfloat16 h = __float2bfloat16(f);
    return *reinterpret_cast<u16*>(&h);
}
static __device__ inline float bf2f(u16 h) {
    union { uint32_t u; float f; } x; x.u = ((uint32_t)h) << 16;
    return x.f;
}
static __device__ inline void split_bf(float x, u16& hi, u16& lo) {
    hi = f2bf(x);
    lo = f2bf(x - bf2f(hi));
}

// ---- shared MFMA inner step (64x64 tile, 4 waves, 2x2 16x16x32 frags, hi/lo 3-term) ----
#define GEMM_PROLOG                                     \
    __shared__ u16 lAh[64 * LSTRIDE];                   \
    __shared__ u16 lAl[64 * LSTRIDE];                   \
    __shared__ u16 lBh[64 * LSTRIDE];                   \
    __shared__ u16 lBl[64 * LSTRIDE];                   \
    const int t    = threadIdx.x;                       \
    const int srow = t >> 2;                            \
    const int kseg = (t & 3) << 3;                      \
    const int lane = t & 63;                            \
    const int wave = t >> 6;                            \
    const int wr   = (wave >> 1) << 5;                  \
    const int wc   = (wave & 1) << 5;                   \
    const int lr   = lane & 15;                         \
    const int lk   = (lane >> 4) << 3;

#define GEMM_MFMA_BLOCK                                                                   \
    __syncthreads();                                                                      \
    {                                                                                     \
        bf16x8 ah0 = *reinterpret_cast<const bf16x8*>(&lAh[(wr + lr) * LSTRIDE + lk]);    \
        bf16x8 ah1 = *reinterpret_cast<const bf16x8*>(&lAh[(wr + 16 + lr) * LSTRIDE + lk]);\
        bf16x8 al0 = *reinterpret_cast<const bf16x8*>(&lAl[(wr + lr) * LSTRIDE + lk]);    \
        bf16x8 al1 = *reinterpret_cast<const bf16x8*>(&lAl[(wr + 16 + lr) * LSTRIDE + lk]);\
        bf16x8 bh0 = *reinterpret_cast<const bf16x8*>(&lBh[(wc + lr) * LSTRIDE + lk]);    \
        bf16x8 bh1 = *reinterpret_cast<const bf16x8*>(&lBh[(wc + 16 + lr) * LSTRIDE + lk]);\
        bf16x8 bl0 = *reinterpret_cast<const bf16x8*>(&lBl[(wc + lr) * LSTRIDE + lk]);    \
        bf16x8 bl1 = *reinterpret_cast<const bf16x8*>(&lBl[(wc + 16 + lr) * LSTRIDE + lk]);\
        acc[0][0] = __builtin_amdgcn_mfma_f32_16x16x32_bf16(ah0, bh0, acc[0][0], 0, 0, 0);\
        acc[0][1] = __builtin_amdgcn_mfma_f32_16x16x32_bf16(ah0, bh1, acc[0][1], 0, 0, 0);\
        acc[1][0] = __builtin_amdgcn_mfma_f32_16x16x32_bf16(ah1, bh0, acc[1][0], 0, 0, 0);\
        acc[1][1] = __builtin_amdgcn_mfma_f32_16x16x32_bf16(ah1, bh1, acc[1][1], 0, 0, 0);\
        acc[0][0] = __builtin_amdgcn_mfma_f32_16x16x32_bf16(al0, bh0, acc[0][0], 0, 0, 0);\
        acc[0][1] = __builtin_amdgcn_mfma_f32_16x16x32_bf16(al0, bh1, acc[0][1], 0, 0, 0);\
        acc[1][0] = __builtin_amdgcn_mfma_f32_16x16x32_bf16(al1, bh0, acc[1][0], 0, 0, 0);\
        acc[1][1] = __builtin_amdgcn_mfma_f32_16x16x32_bf16(al1, bh1, acc[1][1], 0, 0, 0);\
        acc[0][0] = __builtin_amdgcn_mfma_f32_16x16x32_bf16(ah0, bl0, acc[0][0], 0, 0, 0);\
        acc[0][1] = __builtin_amdgcn_mfma_f32_16x16x32_bf16(ah0, bl1, acc[0][1], 0, 0, 0);\
        acc[1][0] = __builtin_amdgcn_mfma_f32_16x16x32_bf16(ah1, bl0, acc[1][0], 0, 0, 0);\
        acc[1][1] = __builtin_amdgcn_mfma_f32_16x16x32_bf16(ah1, bl1, acc[1][1], 0, 0, 0);\
    }                                                                                     \
    __syncthreads();

// A-side from pre-split u16 planes (optionally concat of two sources), B from u16 planes.
__device__ inline void gemm_split(const u16* __restrict__ a1h, const u16* __restrict__ a1l, int lda1, int ka1,
                                  const u16* __restrict__ a2h, const u16* __restrict__ a2l, int lda2,
                                  const u16* __restrict__ bth, const u16* __restrict__ btl, int ldb,
                                  int K, int m0, int n0, f32x4 acc[2][2])
{
    GEMM_PROLOG
    for (int k0 = 0; k0 < K; k0 += 32) {
        const u16 *ah, *al;
        if (k0 < ka1) {
            size_t o = (size_t)(m0 + srow) * lda1 + (k0 + kseg);
            ah = a1h + o; al = a1l + o;
        } else {
            size_t o = (size_t)(m0 + srow) * lda2 + (k0 + kseg - ka1);
            ah = a2h + o; al = a2l + o;
        }
        size_t boff = (size_t)(n0 + srow) * ldb + (k0 + kseg);
        uint4 vah = *reinterpret_cast<const uint4*>(ah);
        uint4 val = *reinterpret_cast<const uint4*>(al);
        uint4 vbh = *reinterpret_cast<const uint4*>(bth + boff);
        uint4 vbl = *reinterpret_cast<const uint4*>(btl + boff);
        *reinterpret_cast<uint4*>(&lAh[srow * LSTRIDE + kseg]) = vah;
        *reinterpret_cast<uint4*>(&lAl[srow * LSTRIDE + kseg]) = val;
        *reinterpret_cast<uint4*>(&lBh[srow * LSTRIDE + kseg]) = vbh;
        *reinterpret_cast<uint4*>(&lBl[srow * LSTRIDE + kseg]) = vbl;
        GEMM_MFMA_BLOCK
    }
}

// A-side staged directly from f32 source (split to hi/lo in registers), B from u16 planes.
__device__ inline void gemm_split_af32(const float* __restrict__ Af, int lda,
                                       const u16* __restrict__ bth, const u16* __restrict__ btl, int ldb,
                                       int K, int m0, int n0, f32x4 acc[2][2])
{
    GEMM_PROLOG
    for (int k0 = 0; k0 < K; k0 += 32) {
        const float* asrc = Af + (size_t)(m0 + srow) * lda + (k0 + kseg);
        float4 f0 = *reinterpret_cast<const float4*>(asrc);
        float4 f1 = *reinterpret_cast<const float4*>(asrc + 4);
        ushort4 h0, l0, h1, l1;
        split_bf(f0.x, h0.x, l0.x); split_bf(f0.y, h0.y, l0.y);
        split_bf(f0.z, h0.z, l0.z); split_bf(f0.w, h0.w, l0.w);
        split_bf(f1.x, h1.x, l1.x); split_bf(f1.y, h1.y, l1.y);
        split_bf(f1.z, h1.z, l1.z); split_bf(f1.w, h1.w, l1.w);
        size_t boff = (size_t)(n0 + srow) * ldb + (k0 + kseg);
        uint4 vbh = *reinterpret_cast<const uint4*>(bth + boff);
        uint4 vbl = *reinterpret_cast<const uint4*>(btl + boff);
        *reinterpret_cast<ushort4*>(&lAh[srow * LSTRIDE + kseg])     = h0;
        *reinterpret_cast<ushort4*>(&lAh[srow * LSTRIDE + kseg + 4]) = h1;
        *reinterpret_cast<ushort4*>(&lAl[srow * LSTRIDE + kseg])     = l0;
        *reinterpret_cast<ushort4*>(&lAl[srow * LSTRIDE + kseg + 4]) = l1;
        *reinterpret_cast<uint4*>(&lBh[srow * LSTRIDE + kseg]) = vbh;
        *reinterpret_cast<uint4*>(&lBl[srow * LSTRIDE + kseg]) = vbl;
        GEMM_MFMA_BLOCK
    }
}

#define EPILOG_COORDS                                   \
    const int lane = threadIdx.x & 63;                  \
    const int wave = threadIdx.x >> 6;                  \
    const int wr = (wave >> 1) << 5;                    \
    const int wc = (wave & 1) << 5;                     \
    const int lr = lane & 15;                           \
    const int l4 = (lane >> 4) << 2;

// projection: per (b,e): C[m][h] = prop[b] @ W[e] + bias[e]; write TRANSPOSED hi/lo
// T*[b][h][e*256+m] so the adjacency GEMM reads it as Bt.
__global__ __launch_bounds__(256) void k_proj(const u16* __restrict__ ph, const u16* __restrict__ pl,
                                              const u16* __restrict__ Wh_, const u16* __restrict__ Wl_,
                                              const float* __restrict__ bias,
                                              u16* __restrict__ oTh, u16* __restrict__ oTl)
{
    const int b = blockIdx.z >> 2, e = blockIdx.z & 3;
    const int m0 = blockIdx.y << 6, n0 = blockIdx.x << 6;
    const u16* A1h = ph + (size_t)b * 256 * 512;
    const u16* A1l = pl + (size_t)b * 256 * 512;
    const u16* Bh  = Wh_ + (size_t)e * 512 * 512;
    const u16* Bl  = Wl_ + (size_t)e * 512 * 512;
    f32x4 acc[2][2] = {};
    gemm_split(A1h, A1l, 512, 512, A1h, A1l, 512, Bh, Bl, 512, 512, m0, n0, acc);
    EPILOG_COORDS
    const size_t tbase = (size_t)b * 512 * 1024 + (size_t)e * 256;
    #pragma unroll
    for (int i = 0; i < 2; ++i)
        #pragma unroll
        for (int j = 0; j < 2; ++j) {
            const int mb  = m0 + wr + i * 16 + l4;
            const int col = n0 + wc + j * 16 + lr;
            const float bia = bias[e * 512 + col];
            ushort4 wh, wl;
            u16 h, l;
            split_bf(acc[i][j][0] + bia, h, l); wh.x = h; wl.x = l;
            split_bf(acc[i][j][1] + bia, h, l); wh.y = h; wl.y = l;
            split_bf(acc[i][j][2] + bia, h, l); wh.z = h; wl.z = l;
            split_bf(acc[i][j][3] + bia, h, l); wh.w = h; wl.w = l;
            *reinterpret_cast<ushort4*>(&oTh[tbase + (size_t)col * 1024 + mb]) = wh;
            *reinterpret_cast<ushort4*>(&oTl[tbase + (size_t)col * 1024 + mb]) = wl;
        }
}

// adjacency: per b: C[n][h] = A_f32[b][:, kOff:+1024] @ T[b]^T; write hi/lo into acat cols colOff..+512
__global__ __launch_bounds__(256) void k_amat(const float* __restrict__ Af,
                                              const u16* __restrict__ Th, const u16* __restrict__ Tl,
                                              u16* __restrict__ ach, u16* __restrict__ acl,
                                              int kOff, int colOff)
{
    const int b = blockIdx.z;
    const int m0 = blockIdx.y << 6, n0 = blockIdx.x << 6;
    const float* A1 = Af + (size_t)b * 256 * 2048 + kOff;
    const u16* Bh  = Th + (size_t)b * 512 * 1024;
    const u16* Bl  = Tl + (size_t)b * 512 * 1024;
    f32x4 acc[2][2] = {};
    gemm_split_af32(A1, 2048, Bh, Bl, 1024, 1024, m0, n0, acc);
    EPILOG_COORDS
    #pragma unroll
    for (int i = 0; i < 2; ++i)
        #pragma unroll
        for (int j = 0; j < 2; ++j) {
            const int mb  = m0 + wr + i * 16 + l4;
            const int col = n0 + wc + j * 16 + lr;
            #pragma unroll
            for (int v = 0; v < 4; ++v) {
                const size_t idx = ((size_t)b * 256 + mb + v) * 1024 + colOff + col;
                u16 h, l;
                split_bf(acc[i][j][v], h, l);
                ach[idx] = h; acl[idx] = l;
            }
        }
}

// gates: G = [a_in|a_out|prop] @ [Wr|Wz] ; r -> rp = hi/lo(sigmoid*prop), z -> z_f32
__global__ __launch_bounds__(256) void k_gates(const u16* __restrict__ ach, const u16* __restrict__ acl,
                                               const u16* __restrict__ ph, const u16* __restrict__ pl,
                                               const u16* __restrict__ Wh_, const u16* __restrict__ Wl_,
                                               const float* __restrict__ br,
                                               const float* __restrict__ bz,
                                               u16* __restrict__ rph, u16* __restrict__ rpl,
                                               float* __restrict__ z_f32)
{
    const int m0 = blockIdx.y << 6, n0 = blockIdx.x << 6;
    f32x4 acc[2][2] = {};
    gemm_split(ach, acl, 1024, 1024, ph, pl, 512, Wh_, Wl_, 1536, 1536, m0, n0, acc);
    EPILOG_COORDS
    #pragma unroll
    for (int i = 0; i < 2; ++i)
        #pragma unroll
        for (int j = 0; j < 2; ++j) {
            const int mb  = m0 + wr + i * 16 + l4;
            const int col = n0 + wc + j * 16 + lr;
            const float bia = (col < 512) ? br[col] : bz[col - 512];
            #pragma unroll
            for (int v = 0; v < 4; ++v) {
                const float x = acc[i][j][v] + bia;
                const float s = 1.0f / (1.0f + __expf(-x));
                const size_t row = (size_t)(mb + v);
                if (col < 512) {
                    const size_t idx = row * 512 + col;
                    const float pf = bf2f(ph[idx]) + bf2f(pl[idx]);
                    u16 h, l;
                    split_bf(s * pf, h, l);
                    rph[idx] = h; rpl[idx] = l;
                } else {
                    z_f32[row * 512 + (col - 512)] = s;
                }
            }
        }
}

// h_hat + GRU update: H = [a_in|a_out|r*prop] @ Wh ; prop = (1-z)*prop + z*tanh(H)
__global__ __launch_bounds__(256) void k_hup(const u16* __restrict__ ach, const u16* __restrict__ acl,
                                             const u16* __restrict__ rph, const u16* __restrict__ rpl,
                                             const u16* __restrict__ Wh_, const u16* __restrict__ Wl_,
                                             const float* __restrict__ bh,
                                             const float* __restrict__ z_f32,
                                             u16* __restrict__ ph, u16* __restrict__ pl)
{
    const int m0 = blockIdx.y << 6, n0 = blockIdx.x << 6;
    f32x4 acc[2][2] = {};
    gemm_split(ach, acl, 1024, 1024, rph, rpl, 512, Wh_, Wl_, 1536, 1536, m0, n0, acc);
    EPILOG_COORDS
    #pragma unroll
    for (int i = 0; i < 2; ++i)
        #pragma unroll
        for (int j = 0; j < 2; ++j) {
            const int mb  = m0 + wr + i * 16 + l4;
            const int col = n0 + wc + j * 16 + lr;
            const float bia = bh[col];
            #pragma unroll
            for (int v = 0; v < 4; ++v) {
                const float hh = tanhf(acc[i][j][v] + bia);
                const size_t idx = (size_t)(mb + v) * 512 + col;
                const float zz = z_f32[idx];
                const float pf = bf2f(ph[idx]) + bf2f(pl[idx]);
                const float pn = (1.0f - zz) * pf + zz * hh;
                u16 h, l;
                split_bf(pn, h, l);
                ph[idx] = h; pl[idx] = l;
            }
        }
}

// final: out = tanh([prop|ann] @ Wo + bo)  (f32 output)
__global__ __launch_bounds__(256) void k_final(const u16* __restrict__ ph, const u16* __restrict__ pl,
                                               const u16* __restrict__ anh, const u16* __restrict__ anl,
                                               const u16* __restrict__ Wh_, const u16* __restrict__ Wl_,
                                               const float* __restrict__ bo,
                                               float* __restrict__ out)
{
    const int m0 = blockIdx.y << 6, n0 = blockIdx.x << 6;
    f32x4 acc[2][2] = {};
    gemm_split(ph, pl, 512, 512, anh, anl, 256, Wh_, Wl_, 768, 768, m0, n0, acc);
    EPILOG_COORDS
    #pragma unroll
    for (int i = 0; i < 2; ++i)
        #pragma unroll
        for (int j = 0; j < 2; ++j) {
            const int mb  = m0 + wr + i * 16 + l4;
            const int col = n0 + wc + j * 16 + lr;
            const float bia = bo[col];
            #pragma unroll
            for (int v = 0; v < 4; ++v)
                out[(size_t)(mb + v) * 512 + col] = tanhf(acc[i][j][v] + bia);
        }
}

// ---- setup kernels ----
__global__ void s_gather(const int* __restrict__ ann, const float* __restrict__ emb,
                         u16* __restrict__ ph, u16* __restrict__ pl,
                         u16* __restrict__ anh, u16* __restrict__ anl)
{
    const int gid = blockIdx.x * 256 + threadIdx.x;  // < 8192*512
    const int row = gid >> 9, d = gid & 511;
    float v = 0.0f;
    if (d < 256) v = emb[(size_t)ann[row] * 256 + d];
    u16 h, l;
    split_bf(v, h, l);
    ph[gid] = h; pl[gid] = l;
    if (d < 256) { anh[((size_t)row << 8) + d] = h; anl[((size_t)row << 8) + d] = l; }
}

// dst[b][o][k] = split(src[b][k][o])
__global__ void s_transpose_split(const float* __restrict__ src, u16* __restrict__ dh,
                                  u16* __restrict__ dl, int O, int K, int total)
{
    const int gid = blockIdx.x * 256 + threadIdx.x;
    if (gid >= total) return;
    const int b = gid / (O * K);
    const int r = gid - b * (O * K);
    const int o = r / K, k = r - o * K;
    u16 h, l;
    split_bf(src[(size_t)b * O * K + (size_t)k * O + o], h, l);
    dh[gid] = h; dl[gid] = l;
}

extern "C" void kernel_launch(void* const* d_in, const int* in_sizes, int n_in,
                              void* d_out, int out_size, void* d_ws, size_t ws_size,
                              hipStream_t stream) {
    const int*   ann   = (const int*)d_in[0];
    const float* A     = (const float*)d_in[1];
    const float* emb   = (const float*)d_in[2];
    const float* W_in  = (const float*)d_in[3];
    const float* b_in  = (const float*)d_in[4];
    const float* W_out = (const float*)d_in[5];
    const float* b_out = (const float*)d_in[6];
    const float* Wr    = (const float*)d_in[7];
    const float* br    = (const float*)d_in[8];
    const float* Wz    = (const float*)d_in[9];
    const float* bz    = (const float*)d_in[10];
    const float* Wh    = (const float*)d_in[11];
    const float* bh    = (const float*)d_in[12];
    const float* Wo    = (const float*)d_in[13];
    const float* bo    = (const float*)d_in[14];
    float* out = (float*)d_out;

    char* ws = (char*)d_ws;
    size_t off = 0;
    auto alloc = [&](size_t bytes) -> void* {
        void* p = ws + off;
        off = (off + bytes + 255) & ~(size_t)255;
        return p;
    };
    float* z_f32 = (float*)alloc(8192ull * 512 * 4);          // 16 MB
    u16* prop_h = (u16*)alloc(8192ull * 512 * 2);             // 8 MB
    u16* prop_l = (u16*)alloc(8192ull * 512 * 2);
    u16* rp_h   = (u16*)alloc(8192ull * 512 * 2);
    u16* rp_l   = (u16*)alloc(8192ull * 512 * 2);
    u16* ann_h  = (u16*)alloc(8192ull * 256 * 2);             // 4 MB
    u16* ann_l  = (u16*)alloc(8192ull * 256 * 2);
    u16* acat_h = (u16*)alloc(8192ull * 1024 * 2);            // 16 MB
    u16* acat_l = (u16*)alloc(8192ull * 1024 * 2);
    u16* T_h    = (u16*)alloc(32ull * 512 * 1024 * 2);        // 32 MB (shared ins/outs)
    u16* T_l    = (u16*)alloc(32ull * 512 * 1024 * 2);
    u16* WiT_h  = (u16*)alloc(4ull * 512 * 512 * 2);
    u16* WiT_l  = (u16*)alloc(4ull * 512 * 512 * 2);
    u16* WoT_h  = (u16*)alloc(4ull * 512 * 512 * 2);
    u16* WoT_l  = (u16*)alloc(4ull * 512 * 512 * 2);
    u16* WrzT_h = (u16*)alloc(1024ull * 1536 * 2);
    u16* WrzT_l = (u16*)alloc(1024ull * 1536 * 2);
    u16* WhT_h  = (u16*)alloc(512ull * 1536 * 2);
    u16* WhT_l  = (u16*)alloc(512ull * 1536 * 2);
    u16* WjT_h  = (u16*)alloc(512ull * 768 * 2);
    u16* WjT_l  = (u16*)alloc(512ull * 768 * 2);
    // total ≈ 170 MB

    s_gather<<<16384, 256, 0, stream>>>(ann, emb, prop_h, prop_l, ann_h, ann_l);
    s_transpose_split<<<(4 * 512 * 512 + 255) / 256, 256, 0, stream>>>(W_in, WiT_h, WiT_l, 512, 512, 4 * 512 * 512);
    s_transpose_split<<<(4 * 512 * 512 + 255) / 256, 256, 0, stream>>>(W_out, WoT_h, WoT_l, 512, 512, 4 * 512 * 512);
    s_transpose_split<<<(512 * 1536 + 255) / 256, 256, 0, stream>>>(Wr, WrzT_h, WrzT_l, 512, 1536, 512 * 1536);
    s_transpose_split<<<(512 * 1536 + 255) / 256, 256, 0, stream>>>(Wz, WrzT_h + 512 * 1536, WrzT_l + 512 * 1536, 512, 1536, 512 * 1536);
    s_transpose_split<<<(512 * 1536 + 255) / 256, 256, 0, stream>>>(Wh, WhT_h, WhT_l, 512, 1536, 512 * 1536);
    s_transpose_split<<<(512 * 768 + 255) / 256, 256, 0, stream>>>(Wo, WjT_h, WjT_l, 512, 768, 512 * 768);

    for (int s = 0; s < 5; ++s) {
        k_proj<<<dim3(8, 4, 128), 256, 0, stream>>>(prop_h, prop_l, WiT_h, WiT_l, b_in, T_h, T_l);
        k_amat<<<dim3(8, 4, 32), 256, 0, stream>>>(A, T_h, T_l, acat_h, acat_l, 0, 0);
        k_proj<<<dim3(8, 4, 128), 256, 0, stream>>>(prop_h, prop_l, WoT_h, WoT_l, b_out, T_h, T_l);
        k_amat<<<dim3(8, 4, 32), 256, 0, stream>>>(A, T_h, T_l, acat_h, acat_l, 1024, 512);
        k_gates<<<dim3(16, 128), 256, 0, stream>>>(acat_h, acat_l, prop_h, prop_l, WrzT_h, WrzT_l, br, bz, rp_h, rp_l, z_f32);
        k_hup<<<dim3(8, 128), 256, 0, stream>>>(acat_h, acat_l, rp_h, rp_l, WhT_h, WhT_l, bh, z_f32, prop_h, prop_l);
    }
    k_final<<<dim3(8, 128), 256, 0, stream>>>(prop_h, prop_l, ann_h, ann_l, WjT_h, WjT_l, bo, out);
}

// Round 4
// 1217.280 us; speedup vs baseline: 2.1206x; 2.1206x over previous
//
#include <hip/hip_runtime.h>
#include <hip/hip_bf16.h>
#include <cstdint>
#include <cstddef>

typedef unsigned short u16;
typedef _Float16 f16;
typedef f16 f16x8 __attribute__((ext_vector_type(8)));
typedef float f32x4 __attribute__((ext_vector_type(4)));

static __device__ inline u16 f2h(float f) {
    f16 h = (f16)f;
    return *reinterpret_cast<u16*>(&h);
}
static __device__ inline float h2f(u16 u) {
    f16 h = *reinterpret_cast<f16*>(&u);
    return (float)h;
}

// async global->LDS, 16B per lane; LDS dest = wave-uniform base + lane*16
#define GLL(g, l) __builtin_amdgcn_global_load_lds(                    \
    (const __attribute__((address_space(1))) void*)(g),                \
    (__attribute__((address_space(3))) void*)(l), 16, 0, 0)

// bijective XCD swizzle (all launches have nwg % 8 == 0)
static __device__ inline int xcd_swz(int fid, int nwg) {
    const int q = nwg >> 3;
    return (fid & 7) * q + (fid >> 3);
}

// stage a 128x32 u16 tile (row-major src, ld in elements) into linear lds[128*32]
static __device__ inline void stage_tile(const u16* __restrict__ src, int ld,
                                         u16* lds, int wave, int lane) {
    const int r = lane >> 2;
    const int c = (lane & 3) << 3;
    const u16* g0 = src + (size_t)(wave * 32 + r) * ld + c;
    GLL(g0, lds + wave * 1024);
    GLL(g0 + (size_t)16 * ld, lds + wave * 1024 + 512);
}

// one K=32 step: wave computes its 64x64 quadrant = 4x4 16x16x32 MFMAs
static __device__ inline void compute32(const u16* lA, const u16* lB,
                                        int wq_r, int wq_c, int lr, int lk,
                                        f32x4 acc[4][4]) {
    f16x8 a[4], b[4];
    #pragma unroll
    for (int i = 0; i < 4; ++i)
        a[i] = *reinterpret_cast<const f16x8*>(&lA[(wq_r + i * 16 + lr) * 32 + lk]);
    #pragma unroll
    for (int j = 0; j < 4; ++j)
        b[j] = *reinterpret_cast<const f16x8*>(&lB[(wq_c + j * 16 + lr) * 32 + lk]);
    #pragma unroll
    for (int i = 0; i < 4; ++i)
        #pragma unroll
        for (int j = 0; j < 4; ++j)
            acc[i][j] = __builtin_amdgcn_mfma_f32_16x16x32_f16(a[i], b[j], acc[i][j], 0, 0, 0);
}

// C[128x128] = concat(a1,a2)[M x K] @ bt[N x K]^T ; u16(f16) sources, dbuf 2-phase
static __device__ inline void gemm128(const u16* __restrict__ a1, int lda1, int ka1,
                                      const u16* __restrict__ a2, int lda2,
                                      const u16* __restrict__ bt, int ldb,
                                      int K, int m0, int n0,
                                      u16* sA, u16* sB, f32x4 acc[4][4])
{
    const int t = threadIdx.x, lane = t & 63, wave = t >> 6;
    const int lr = lane & 15, lk = (lane >> 4) << 3;
    const int wq_r = (wave >> 1) << 6, wq_c = (wave & 1) << 6;
    const int nt = K >> 5;
    stage_tile(a1 + (size_t)m0 * lda1, lda1, sA, wave, lane);
    stage_tile(bt + (size_t)n0 * ldb, ldb, sB, wave, lane);
    __syncthreads();
    int buf = 0;
    for (int ti = 0; ti < nt; ++ti) {
        const int k1 = (ti + 1) << 5;
        if (k1 < K) {
            const u16* s;
            int ld;
            if (k1 < ka1) { s = a1 + (size_t)m0 * lda1 + k1;        ld = lda1; }
            else          { s = a2 + (size_t)m0 * lda2 + (k1 - ka1); ld = lda2; }
            stage_tile(s, ld, sA + (buf ^ 1) * 4096, wave, lane);
            stage_tile(bt + (size_t)n0 * ldb + k1, ldb, sB + (buf ^ 1) * 4096, wave, lane);
        }
        compute32(sA + buf * 4096, sB + buf * 4096, wq_r, wq_c, lr, lk, acc);
        __syncthreads();
        buf ^= 1;
    }
}

// same but A staged from f32 source (reg convert), B via global_load_lds
static __device__ inline void gemm128_af32(const float* __restrict__ Af, int lda,
                                           const u16* __restrict__ bt, int ldb,
                                           int K, int m0, int n0,
                                           u16* sA, u16* sB, f32x4 acc[4][4])
{
    const int t = threadIdx.x, lane = t & 63, wave = t >> 6;
    const int lr = lane & 15, lk = (lane >> 4) << 3;
    const int wq_r = (wave >> 1) << 6, wq_c = (wave & 1) << 6;
    const int ar = t >> 1, ac = (t & 1) << 4;
    const float* arow = Af + (size_t)(m0 + ar) * lda + ac;
    const int nt = K >> 5;
    {
        float4 f0 = *(const float4*)(arow);
        float4 f1 = *(const float4*)(arow + 4);
        float4 f2 = *(const float4*)(arow + 8);
        float4 f3 = *(const float4*)(arow + 12);
        ushort4 p0 = { f2h(f0.x), f2h(f0.y), f2h(f0.z), f2h(f0.w) };
        ushort4 p1 = { f2h(f1.x), f2h(f1.y), f2h(f1.z), f2h(f1.w) };
        ushort4 p2 = { f2h(f2.x), f2h(f2.y), f2h(f2.z), f2h(f2.w) };
        ushort4 p3 = { f2h(f3.x), f2h(f3.y), f2h(f3.z), f2h(f3.w) };
        *reinterpret_cast<ushort4*>(&sA[ar * 32 + ac])      = p0;
        *reinterpret_cast<ushort4*>(&sA[ar * 32 + ac + 4])  = p1;
        *reinterpret_cast<ushort4*>(&sA[ar * 32 + ac + 8])  = p2;
        *reinterpret_cast<ushort4*>(&sA[ar * 32 + ac + 12]) = p3;
        stage_tile(bt + (size_t)n0 * ldb, ldb, sB, wave, lane);
    }
    __syncthreads();
    int buf = 0;
    for (int ti = 0; ti < nt; ++ti) {
        const int k1 = (ti + 1) << 5;
        const bool pre = k1 < K;
        float4 f0, f1, f2, f3;
        if (pre) {
            const float* s = arow + k1;
            f0 = *(const float4*)(s);
            f1 = *(const float4*)(s + 4);
            f2 = *(const float4*)(s + 8);
            f3 = *(const float4*)(s + 12);
            stage_tile(bt + (size_t)n0 * ldb + k1, ldb, sB + (buf ^ 1) * 4096, wave, lane);
        }
        compute32(sA + buf * 4096, sB + buf * 4096, wq_r, wq_c, lr, lk, acc);
        if (pre) {
            u16* d = sA + (buf ^ 1) * 4096 + ar * 32 + ac;
            ushort4 p0 = { f2h(f0.x), f2h(f0.y), f2h(f0.z), f2h(f0.w) };
            ushort4 p1 = { f2h(f1.x), f2h(f1.y), f2h(f1.z), f2h(f1.w) };
            ushort4 p2 = { f2h(f2.x), f2h(f2.y), f2h(f2.z), f2h(f2.w) };
            ushort4 p3 = { f2h(f3.x), f2h(f3.y), f2h(f3.z), f2h(f3.w) };
            *reinterpret_cast<ushort4*>(d)      = p0;
            *reinterpret_cast<ushort4*>(d + 4)  = p1;
            *reinterpret_cast<ushort4*>(d + 8)  = p2;
            *reinterpret_cast<ushort4*>(d + 12) = p3;
        }
        __syncthreads();
        buf ^= 1;
    }
}

#define EPI                                         \
    const int lane = threadIdx.x & 63;              \
    const int wave = threadIdx.x >> 6;              \
    const int wq_r = (wave >> 1) << 6;              \
    const int wq_c = (wave & 1) << 6;               \
    const int lr = lane & 15;                       \
    const int l4 = (lane >> 4) << 2;

// projection: per (b,e): C = prop[b] @ W[e] + bias[e]; write transposed T[b][h][e*256+m]
__global__ __launch_bounds__(256, 2) void k_proj(const u16* __restrict__ P,
                                                 const u16* __restrict__ W,
                                                 const float* __restrict__ bias,
                                                 u16* __restrict__ oT)
{
    __shared__ u16 sA[2 * 4096], sB[2 * 4096];
    const int fid = xcd_swz(blockIdx.x, gridDim.x);
    const int n = fid & 3, m = (fid >> 2) & 1, be = fid >> 3;
    const int b = be >> 2, e = be & 3;
    const int m0 = m << 7, n0 = n << 7;
    const u16* A1 = P + (size_t)b * (256 * 512);
    const u16* Bt = W + (size_t)e * (512 * 512);
    f32x4 acc[4][4] = {};
    gemm128(A1, 512, 512, A1, 512, Bt, 512, 512, m0, n0, sA, sB, acc);
    EPI
    u16* base = oT + (size_t)b * 512 * 1024 + (size_t)e * 256;
    #pragma unroll
    for (int i = 0; i < 4; ++i) {
        const int row = m0 + wq_r + i * 16 + l4;
        #pragma unroll
        for (int j = 0; j < 4; ++j) {
            const int col = n0 + wq_c + j * 16 + lr;
            const float bia = bias[e * 512 + col];
            ushort4 w4;
            w4.x = f2h(acc[i][j][0] + bia);
            w4.y = f2h(acc[i][j][1] + bia);
            w4.z = f2h(acc[i][j][2] + bia);
            w4.w = f2h(acc[i][j][3] + bia);
            *reinterpret_cast<ushort4*>(&base[(size_t)col * 1024 + row]) = w4;
        }
    }
}

// adjacency: per b: C = A_f32[b][:, kOff:+1024] @ T[b]^T -> acat cols colOff..+512
__global__ __launch_bounds__(256, 2) void k_amat(const float* __restrict__ Af,
                                                 const u16* __restrict__ T,
                                                 u16* __restrict__ acat,
                                                 int kOff, int colOff)
{
    __shared__ u16 sA[2 * 4096], sB[2 * 4096];
    const int fid = xcd_swz(blockIdx.x, gridDim.x);
    const int n = fid & 3, m = (fid >> 2) & 1, b = fid >> 3;
    const int m0 = m << 7, n0 = n << 7;
    const float* A1 = Af + (size_t)b * 256 * 2048 + kOff;
    const u16* Bt = T + (size_t)b * 512 * 1024;
    f32x4 acc[4][4] = {};
    gemm128_af32(A1, 2048, Bt, 1024, 1024, m0, n0, sA, sB, acc);
    EPI
    #pragma unroll
    for (int i = 0; i < 4; ++i) {
        const int row = m0 + wq_r + i * 16 + l4;
        #pragma unroll
        for (int j = 0; j < 4; ++j) {
            const int col = n0 + wq_c + j * 16 + lr;
            #pragma unroll
            for (int v = 0; v < 4; ++v)
                acat[((size_t)b * 256 + row + v) * 1024 + colOff + col] = f2h(acc[i][j][v]);
        }
    }
}

// gates: G = [acat | prop] @ Wrz^T ; col<512 -> rp = f16(sigmoid*prop) ; else z=f32 sigmoid
__global__ __launch_bounds__(256, 2) void k_gates(const u16* __restrict__ acat,
                                                  const u16* __restrict__ P,
                                                  const u16* __restrict__ Wrz,
                                                  const float* __restrict__ br,
                                                  const float* __restrict__ bz,
                                                  u16* __restrict__ rp,
                                                  float* __restrict__ z)
{
    __shared__ u16 sA[2 * 4096], sB[2 * 4096];
    const int fid = xcd_swz(blockIdx.x, gridDim.x);
    const int n = fid & 7, m = fid >> 3;
    const int m0 = m << 7, n0 = n << 7;
    f32x4 acc[4][4] = {};
    gemm128(acat, 1024, 1024, P, 512, Wrz, 1536, 1536, m0, n0, sA, sB, acc);
    EPI
    #pragma unroll
    for (int i = 0; i < 4; ++i) {
        const int row = m0 + wq_r + i * 16 + l4;
        #pragma unroll
        for (int j = 0; j < 4; ++j) {
            const int col = n0 + wq_c + j * 16 + lr;
            const float bia = (col < 512) ? br[col] : bz[col - 512];
            #pragma unroll
            for (int v = 0; v < 4; ++v) {
                const float x = acc[i][j][v] + bia;
                const float s = 1.0f / (1.0f + __expf(-x));
                if (col < 512) {
                    const size_t idx = (size_t)(row + v) * 512 + col;
                    rp[idx] = f2h(s * h2f(P[idx]));
                } else {
                    z[(size_t)(row + v) * 512 + (col - 512)] = s;
                }
            }
        }
    }
}

// h_hat + GRU update: H = [acat | rp] @ Wh^T ; prop = (1-z)*prop + z*tanh(H)
__global__ __launch_bounds__(256, 2) void k_hup(const u16* __restrict__ acat,
                                                const u16* __restrict__ rp,
                                                const u16* __restrict__ Wh_,
                                                const float* __restrict__ bh,
                                                const float* __restrict__ z,
                                                u16* __restrict__ P)
{
    __shared__ u16 sA[2 * 4096], sB[2 * 4096];
    const int fid = xcd_swz(blockIdx.x, gridDim.x);
    const int n = fid & 3, m = fid >> 2;
    const int m0 = m << 7, n0 = n << 7;
    f32x4 acc[4][4] = {};
    gemm128(acat, 1024, 1024, rp, 512, Wh_, 1536, 1536, m0, n0, sA, sB, acc);
    EPI
    #pragma unroll
    for (int i = 0; i < 4; ++i) {
        const int row = m0 + wq_r + i * 16 + l4;
        #pragma unroll
        for (int j = 0; j < 4; ++j) {
            const int col = n0 + wq_c + j * 16 + lr;
            const float bia = bh[col];
            #pragma unroll
            for (int v = 0; v < 4; ++v) {
                const float hh = tanhf(acc[i][j][v] + bia);
                const size_t idx = (size_t)(row + v) * 512 + col;
                const float zz = z[idx];
                const float pn = (1.0f - zz) * h2f(P[idx]) + zz * hh;
                P[idx] = f2h(pn);
            }
        }
    }
}

// final: out = tanh([prop | ann] @ Wo^T + bo) (f32)
__global__ __launch_bounds__(256, 2) void k_final(const u16* __restrict__ P,
                                                  const u16* __restrict__ annf,
                                                  const u16* __restrict__ Wj,
                                                  const float* __restrict__ bo,
                                                  float* __restrict__ out)
{
    __shared__ u16 sA[2 * 4096], sB[2 * 4096];
    const int fid = xcd_swz(blockIdx.x, gridDim.x);
    const int n = fid & 3, m = fid >> 2;
    const int m0 = m << 7, n0 = n << 7;
    f32x4 acc[4][4] = {};
    gemm128(P, 512, 512, annf, 256, Wj, 768, 768, m0, n0, sA, sB, acc);
    EPI
    #pragma unroll
    for (int i = 0; i < 4; ++i) {
        const int row = m0 + wq_r + i * 16 + l4;
        #pragma unroll
        for (int j = 0; j < 4; ++j) {
            const int col = n0 + wq_c + j * 16 + lr;
            const float bia = bo[col];
            #pragma unroll
            for (int v = 0; v < 4; ++v)
                out[(size_t)(row + v) * 512 + col] = tanhf(acc[i][j][v] + bia);
        }
    }
}

// ---- setup ----
__global__ void s_gather(const int* __restrict__ ann, const float* __restrict__ emb,
                         u16* __restrict__ P, u16* __restrict__ annf)
{
    const int gid = blockIdx.x * 256 + threadIdx.x;  // < 8192*512
    const int row = gid >> 9, d = gid & 511;
    float v = 0.0f;
    if (d < 256) v = emb[(size_t)ann[row] * 256 + d];
    const u16 h = f2h(v);
    P[gid] = h;
    if (d < 256) annf[((size_t)row << 8) + d] = h;
}

// dst[b][o][k] = f16(src[b][k][o])
__global__ void s_transpose(const float* __restrict__ src, u16* __restrict__ dst,
                            int O, int K, int total)
{
    const int gid = blockIdx.x * 256 + threadIdx.x;
    if (gid >= total) return;
    const int b = gid / (O * K);
    const int r = gid - b * (O * K);
    const int o = r / K, k = r - o * K;
    dst[gid] = f2h(src[(size_t)b * O * K + (size_t)k * O + o]);
}

extern "C" void kernel_launch(void* const* d_in, const int* in_sizes, int n_in,
                              void* d_out, int out_size, void* d_ws, size_t ws_size,
                              hipStream_t stream) {
    const int*   ann   = (const int*)d_in[0];
    const float* A     = (const float*)d_in[1];
    const float* emb   = (const float*)d_in[2];
    const float* W_in  = (const float*)d_in[3];
    const float* b_in  = (const float*)d_in[4];
    const float* W_out = (const float*)d_in[5];
    const float* b_out = (const float*)d_in[6];
    const float* Wr    = (const float*)d_in[7];
    const float* br    = (const float*)d_in[8];
    const float* Wz    = (const float*)d_in[9];
    const float* bz    = (const float*)d_in[10];
    const float* Wh    = (const float*)d_in[11];
    const float* bh    = (const float*)d_in[12];
    const float* Wo    = (const float*)d_in[13];
    const float* bo    = (const float*)d_in[14];
    float* out = (float*)d_out;

    char* ws = (char*)d_ws;
    size_t off = 0;
    auto alloc = [&](size_t bytes) -> void* {
        void* p = ws + off;
        off = (off + bytes + 255) & ~(size_t)255;
        return p;
    };
    float* z_f32 = (float*)alloc(8192ull * 512 * 4);   // 16 MB
    u16* P     = (u16*)alloc(8192ull * 512 * 2);       // 8 MB
    u16* rp    = (u16*)alloc(8192ull * 512 * 2);       // 8 MB
    u16* annf  = (u16*)alloc(8192ull * 256 * 2);       // 4 MB
    u16* acat  = (u16*)alloc(8192ull * 1024 * 2);      // 16 MB
    u16* T     = (u16*)alloc(32ull * 512 * 1024 * 2);  // 32 MB
    u16* WiT   = (u16*)alloc(4ull * 512 * 512 * 2);
    u16* WoT   = (u16*)alloc(4ull * 512 * 512 * 2);
    u16* WrzT  = (u16*)alloc(1024ull * 1536 * 2);
    u16* WhT   = (u16*)alloc(512ull * 1536 * 2);
    u16* WjT   = (u16*)alloc(512ull * 768 * 2);
    // total ~93 MB

    s_gather<<<16384, 256, 0, stream>>>(ann, emb, P, annf);
    s_transpose<<<(4 * 512 * 512 + 255) / 256, 256, 0, stream>>>(W_in, WiT, 512, 512, 4 * 512 * 512);
    s_transpose<<<(4 * 512 * 512 + 255) / 256, 256, 0, stream>>>(W_out, WoT, 512, 512, 4 * 512 * 512);
    s_transpose<<<(512 * 1536 + 255) / 256, 256, 0, stream>>>(Wr, WrzT, 512, 1536, 512 * 1536);
    s_transpose<<<(512 * 1536 + 255) / 256, 256, 0, stream>>>(Wz, WrzT + 512 * 1536, 512, 1536, 512 * 1536);
    s_transpose<<<(512 * 1536 + 255) / 256, 256, 0, stream>>>(Wh, WhT, 512, 1536, 512 * 1536);
    s_transpose<<<(512 * 768 + 255) / 256, 256, 0, stream>>>(Wo, WjT, 512, 768, 512 * 768);

    for (int s = 0; s < 5; ++s) {
        k_proj<<<1024, 256, 0, stream>>>(P, WiT, b_in, T);
        k_amat<<<256, 256, 0, stream>>>(A, T, acat, 0, 0);
        k_proj<<<1024, 256, 0, stream>>>(P, WoT, b_out, T);
        k_amat<<<256, 256, 0, stream>>>(A, T, acat, 1024, 512);
        k_gates<<<512, 256, 0, stream>>>(acat, P, WrzT, br, bz, rp, z_f32);
        k_hup<<<256, 256, 0, stream>>>(acat, rp, WhT, bh, z_f32, P);
    }
    k_final<<<256, 256, 0, stream>>>(P, annf, WjT, bo, out);
}

// Round 5
// 1016.810 us; speedup vs baseline: 2.5387x; 1.1972x over previous
//
#include <hip/hip_runtime.h>
#include <hip/hip_bf16.h>
#include <cstdint>
#include <cstddef>

typedef unsigned short u16;
typedef _Float16 f16;
typedef f16 f16x8 __attribute__((ext_vector_type(8)));
typedef float f32x4 __attribute__((ext_vector_type(4)));

static __device__ inline u16 f2h(float f) {
    f16 h = (f16)f;
    return *reinterpret_cast<u16*>(&h);
}
static __device__ inline float h2f(u16 u) {
    f16 h = *reinterpret_cast<f16*>(&u);
    return (float)h;
}

// async global->LDS, 16B per lane; LDS dest = wave-uniform base + lane*16
#define GLL(g, l) __builtin_amdgcn_global_load_lds(                    \
    (const __attribute__((address_space(1))) void*)(g),                \
    (__attribute__((address_space(3))) void*)(l), 16, 0, 0)

// bijective XCD swizzle (all grids % 8 == 0)
static __device__ inline int xcd_swz(int fid, int nwg) {
    const int q = nwg >> 3;
    return (fid & 7) * q + (fid >> 3);
}

// stage a 128x32 u16 tile (row-major src, ld elements) into linear lds[128*32]
static __device__ inline void stage_tile(const u16* __restrict__ src, int ld,
                                         u16* lds, int wave, int lane) {
    const int r = lane >> 2;
    const int c = (lane & 3) << 3;
    const u16* g0 = src + (size_t)(wave * 32 + r) * ld + c;
    GLL(g0, lds + wave * 1024);
    GLL(g0 + (size_t)16 * ld, lds + wave * 1024 + 512);
}

// one K=32 step: wave computes its 64x64 quadrant = 4x4 16x16x32 MFMAs
static __device__ inline void compute32(const u16* lA, const u16* lB,
                                        int wq_r, int wq_c, int lr, int lk,
                                        f32x4 acc[4][4]) {
    f16x8 a[4], b[4];
    #pragma unroll
    for (int i = 0; i < 4; ++i)
        a[i] = *reinterpret_cast<const f16x8*>(&lA[(wq_r + i * 16 + lr) * 32 + lk]);
    #pragma unroll
    for (int j = 0; j < 4; ++j)
        b[j] = *reinterpret_cast<const f16x8*>(&lB[(wq_c + j * 16 + lr) * 32 + lk]);
    #pragma unroll
    for (int i = 0; i < 4; ++i)
        #pragma unroll
        for (int j = 0; j < 4; ++j)
            acc[i][j] = __builtin_amdgcn_mfma_f32_16x16x32_f16(a[i], b[j], acc[i][j], 0, 0, 0);
}

// C[128x128] = concat(a1,a2)[M x K] @ bt[N x K]^T ; u16(f16) sources, dbuf 2-phase
static __device__ inline void gemm128(const u16* __restrict__ a1, int lda1, int ka1,
                                      const u16* __restrict__ a2, int lda2,
                                      const u16* __restrict__ bt, int ldb,
                                      int K, int m0, int n0,
                                      u16* sA, u16* sB, f32x4 acc[4][4])
{
    const int t = threadIdx.x, lane = t & 63, wave = t >> 6;
    const int lr = lane & 15, lk = (lane >> 4) << 3;
    const int wq_r = (wave >> 1) << 6, wq_c = (wave & 1) << 6;
    const int nt = K >> 5;
    stage_tile(a1 + (size_t)m0 * lda1, lda1, sA, wave, lane);
    stage_tile(bt + (size_t)n0 * ldb, ldb, sB, wave, lane);
    __syncthreads();
    int buf = 0;
    for (int ti = 0; ti < nt; ++ti) {
        const int k1 = (ti + 1) << 5;
        if (k1 < K) {
            const u16* s;
            int ld;
            if (k1 < ka1) { s = a1 + (size_t)m0 * lda1 + k1;        ld = lda1; }
            else          { s = a2 + (size_t)m0 * lda2 + (k1 - ka1); ld = lda2; }
            stage_tile(s, ld, sA + (buf ^ 1) * 4096, wave, lane);
            stage_tile(bt + (size_t)n0 * ldb + k1, ldb, sB + (buf ^ 1) * 4096, wave, lane);
        }
        compute32(sA + buf * 4096, sB + buf * 4096, wq_r, wq_c, lr, lk, acc);
        __syncthreads();
        buf ^= 1;
    }
}

// same but A staged from f32 source (reg convert), B via global_load_lds
static __device__ inline void gemm128_af32(const float* __restrict__ Af, int lda,
                                           const u16* __restrict__ bt, int ldb,
                                           int K, int m0, int n0,
                                           u16* sA, u16* sB, f32x4 acc[4][4])
{
    const int t = threadIdx.x, lane = t & 63, wave = t >> 6;
    const int lr = lane & 15, lk = (lane >> 4) << 3;
    const int wq_r = (wave >> 1) << 6, wq_c = (wave & 1) << 6;
    const int ar = t >> 1, ac = (t & 1) << 4;
    const float* arow = Af + (size_t)(m0 + ar) * lda + ac;
    const int nt = K >> 5;
    {
        float4 f0 = *(const float4*)(arow);
        float4 f1 = *(const float4*)(arow + 4);
        float4 f2 = *(const float4*)(arow + 8);
        float4 f3 = *(const float4*)(arow + 12);
        ushort4 p0 = { f2h(f0.x), f2h(f0.y), f2h(f0.z), f2h(f0.w) };
        ushort4 p1 = { f2h(f1.x), f2h(f1.y), f2h(f1.z), f2h(f1.w) };
        ushort4 p2 = { f2h(f2.x), f2h(f2.y), f2h(f2.z), f2h(f2.w) };
        ushort4 p3 = { f2h(f3.x), f2h(f3.y), f2h(f3.z), f2h(f3.w) };
        *reinterpret_cast<ushort4*>(&sA[ar * 32 + ac])      = p0;
        *reinterpret_cast<ushort4*>(&sA[ar * 32 + ac + 4])  = p1;
        *reinterpret_cast<ushort4*>(&sA[ar * 32 + ac + 8])  = p2;
        *reinterpret_cast<ushort4*>(&sA[ar * 32 + ac + 12]) = p3;
        stage_tile(bt + (size_t)n0 * ldb, ldb, sB, wave, lane);
    }
    __syncthreads();
    int buf = 0;
    for (int ti = 0; ti < nt; ++ti) {
        const int k1 = (ti + 1) << 5;
        const bool pre = k1 < K;
        float4 f0, f1, f2, f3;
        if (pre) {
            const float* s = arow + k1;
            f0 = *(const float4*)(s);
            f1 = *(const float4*)(s + 4);
            f2 = *(const float4*)(s + 8);
            f3 = *(const float4*)(s + 12);
            stage_tile(bt + (size_t)n0 * ldb + k1, ldb, sB + (buf ^ 1) * 4096, wave, lane);
        }
        compute32(sA + buf * 4096, sB + buf * 4096, wq_r, wq_c, lr, lk, acc);
        if (pre) {
            u16* d = sA + (buf ^ 1) * 4096 + ar * 32 + ac;
            ushort4 p0 = { f2h(f0.x), f2h(f0.y), f2h(f0.z), f2h(f0.w) };
            ushort4 p1 = { f2h(f1.x), f2h(f1.y), f2h(f1.z), f2h(f1.w) };
            ushort4 p2 = { f2h(f2.x), f2h(f2.y), f2h(f2.z), f2h(f2.w) };
            ushort4 p3 = { f2h(f3.x), f2h(f3.y), f2h(f3.z), f2h(f3.w) };
            *reinterpret_cast<ushort4*>(d)      = p0;
            *reinterpret_cast<ushort4*>(d + 4)  = p1;
            *reinterpret_cast<ushort4*>(d + 8)  = p2;
            *reinterpret_cast<ushort4*>(d + 12) = p3;
        }
        __syncthreads();
        buf ^= 1;
    }
}

#define EPI                                         \
    const int lane = threadIdx.x & 63;              \
    const int wave = threadIdx.x >> 6;              \
    const int wq_r = (wave >> 1) << 6;              \
    const int wq_c = (wave & 1) << 6;               \
    const int lr = lane & 15;                       \
    const int l4 = (lane >> 4) << 2;

#define TDIR (32ull * 512 * 1024)

// mega-projection: C[8192 x 4096] = P @ WioT^T ; col = dir*2048 + e*512 + h
// write transposed: T[dir][b][h][e*256+m]
__global__ __launch_bounds__(256, 4) void k_proj(const u16* __restrict__ P,
                                                 const u16* __restrict__ Wio,
                                                 const float* __restrict__ b_in,
                                                 const float* __restrict__ b_out,
                                                 u16* __restrict__ T)
{
    __shared__ u16 sA[2 * 4096], sB[2 * 4096];
    const int fid = xcd_swz(blockIdx.x, gridDim.x);
    const int n = fid & 31, m = fid >> 5;
    const int m0 = m << 7, n0 = n << 7;
    f32x4 acc[4][4] = {};
    gemm128(P, 512, 512, P, 512, Wio, 512, 512, m0, n0, sA, sB, acc);
    EPI
    #pragma unroll
    for (int i = 0; i < 4; ++i) {
        const int row = m0 + wq_r + i * 16 + l4;
        const int b = row >> 8, mm = row & 255;
        #pragma unroll
        for (int j = 0; j < 4; ++j) {
            const int col = n0 + wq_c + j * 16 + lr;
            const int dir = col >> 11, eh = col & 2047;
            const float bia = (dir ? b_out : b_in)[eh];
            const int e = eh >> 9, h = eh & 511;
            ushort4 w4;
            w4.x = f2h(acc[i][j][0] + bia);
            w4.y = f2h(acc[i][j][1] + bia);
            w4.z = f2h(acc[i][j][2] + bia);
            w4.w = f2h(acc[i][j][3] + bia);
            u16* dst = T + (size_t)dir * TDIR + (size_t)b * 512 * 1024 + (size_t)h * 1024 + e * 256 + mm;
            *reinterpret_cast<ushort4*>(dst) = w4;
        }
    }
}

// adjacency: per (b,dir): C = A_f32[b][:, dir*1024:+1024] @ T[dir][b]^T -> acat cols dir*512..+512
__global__ __launch_bounds__(256, 4) void k_amat(const float* __restrict__ Af,
                                                 const u16* __restrict__ T,
                                                 u16* __restrict__ acat)
{
    __shared__ u16 sA[2 * 4096], sB[2 * 4096];
    const int fid = xcd_swz(blockIdx.x, gridDim.x);
    const int n = fid & 3, m = (fid >> 2) & 1, bd = fid >> 3;
    const int b = bd >> 1, dir = bd & 1;
    const int m0 = m << 7, n0 = n << 7;
    const float* A1 = Af + (size_t)b * 256 * 2048 + dir * 1024;
    const u16* Bt = T + (size_t)dir * TDIR + (size_t)b * 512 * 1024;
    f32x4 acc[4][4] = {};
    gemm128_af32(A1, 2048, Bt, 1024, 1024, m0, n0, sA, sB, acc);
    EPI
    #pragma unroll
    for (int i = 0; i < 4; ++i) {
        const int row = m0 + wq_r + i * 16 + l4;
        #pragma unroll
        for (int j = 0; j < 4; ++j) {
            const int col = n0 + wq_c + j * 16 + lr;
            #pragma unroll
            for (int v = 0; v < 4; ++v)
                acat[((size_t)b * 256 + row + v) * 1024 + dir * 512 + col] = f2h(acc[i][j][v]);
        }
    }
}

// gates: X[8192 x 1536] = [acat | P] @ Wrzh^T  (Wrzh h-block zero-padded over P rows)
// n<512: rp = f16(sigmoid(X+br)*P) ; n<1024: z = sigmoid(X+bz) ; else hpart = X (f32, no bias)
__global__ __launch_bounds__(256, 4) void k_gates(const u16* __restrict__ acat,
                                                  const u16* __restrict__ P,
                                                  const u16* __restrict__ Wrzh,
                                                  const float* __restrict__ br,
                                                  const float* __restrict__ bz,
                                                  u16* __restrict__ rp,
                                                  float* __restrict__ z,
                                                  float* __restrict__ hpart)
{
    __shared__ u16 sA[2 * 4096], sB[2 * 4096];
    const int fid = xcd_swz(blockIdx.x, gridDim.x);
    const int n = fid % 12, m = fid / 12;
    const int m0 = m << 7, n0 = n << 7;
    f32x4 acc[4][4] = {};
    gemm128(acat, 1024, 1024, P, 512, Wrzh, 1536, 1536, m0, n0, sA, sB, acc);
    EPI
    #pragma unroll
    for (int i = 0; i < 4; ++i) {
        const int row = m0 + wq_r + i * 16 + l4;
        #pragma unroll
        for (int j = 0; j < 4; ++j) {
            const int col = n0 + wq_c + j * 16 + lr;
            if (col < 512) {
                const float bia = br[col];
                #pragma unroll
                for (int v = 0; v < 4; ++v) {
                    const float s = 1.0f / (1.0f + __expf(-(acc[i][j][v] + bia)));
                    const size_t idx = (size_t)(row + v) * 512 + col;
                    rp[idx] = f2h(s * h2f(P[idx]));
                }
            } else if (col < 1024) {
                const float bia = bz[col - 512];
                #pragma unroll
                for (int v = 0; v < 4; ++v)
                    z[(size_t)(row + v) * 512 + (col - 512)] =
                        1.0f / (1.0f + __expf(-(acc[i][j][v] + bia)));
            } else {
                #pragma unroll
                for (int v = 0; v < 4; ++v)
                    hpart[(size_t)(row + v) * 512 + (col - 1024)] = acc[i][j][v];
            }
        }
    }
}

// h/update: Y = rp @ WhP^T (K=512) ; h = tanh(hpart + Y + bh) ; P = (1-z)P + z h
__global__ __launch_bounds__(256, 4) void k_hup(const u16* __restrict__ rp,
                                                const u16* __restrict__ WhP,
                                                const float* __restrict__ bh,
                                                const float* __restrict__ z,
                                                const float* __restrict__ hpart,
                                                u16* __restrict__ P)
{
    __shared__ u16 sA[2 * 4096], sB[2 * 4096];
    const int fid = xcd_swz(blockIdx.x, gridDim.x);
    const int n = fid & 3, m = fid >> 2;
    const int m0 = m << 7, n0 = n << 7;
    f32x4 acc[4][4] = {};
    gemm128(rp, 512, 512, rp, 512, WhP, 512, 512, m0, n0, sA, sB, acc);
    EPI
    #pragma unroll
    for (int i = 0; i < 4; ++i) {
        const int row = m0 + wq_r + i * 16 + l4;
        #pragma unroll
        for (int j = 0; j < 4; ++j) {
            const int col = n0 + wq_c + j * 16 + lr;
            const float bia = bh[col];
            #pragma unroll
            for (int v = 0; v < 4; ++v) {
                const size_t idx = (size_t)(row + v) * 512 + col;
                const float hh = tanhf(hpart[idx] + acc[i][j][v] + bia);
                const float zz = z[idx];
                const float pn = (1.0f - zz) * h2f(P[idx]) + zz * hh;
                P[idx] = f2h(pn);
            }
        }
    }
}

// final: out = tanh([P | ann] @ Wj^T + bo) (f32)
__global__ __launch_bounds__(256, 4) void k_final(const u16* __restrict__ P,
                                                  const u16* __restrict__ annf,
                                                  const u16* __restrict__ Wj,
                                                  const float* __restrict__ bo,
                                                  float* __restrict__ out)
{
    __shared__ u16 sA[2 * 4096], sB[2 * 4096];
    const int fid = xcd_swz(blockIdx.x, gridDim.x);
    const int n = fid & 3, m = fid >> 2;
    const int m0 = m << 7, n0 = n << 7;
    f32x4 acc[4][4] = {};
    gemm128(P, 512, 512, annf, 256, Wj, 768, 768, m0, n0, sA, sB, acc);
    EPI
    #pragma unroll
    for (int i = 0; i < 4; ++i) {
        const int row = m0 + wq_r + i * 16 + l4;
        #pragma unroll
        for (int j = 0; j < 4; ++j) {
            const int col = n0 + wq_c + j * 16 + lr;
            const float bia = bo[col];
            #pragma unroll
            for (int v = 0; v < 4; ++v)
                out[(size_t)(row + v) * 512 + col] = tanhf(acc[i][j][v] + bia);
        }
    }
}

// ---- setup ----
__global__ void s_gather(const int* __restrict__ ann, const float* __restrict__ emb,
                         u16* __restrict__ P, u16* __restrict__ annf)
{
    const int gid = blockIdx.x * 256 + threadIdx.x;  // < 8192*512
    const int row = gid >> 9, d = gid & 511;
    float v = 0.0f;
    if (d < 256) v = emb[(size_t)ann[row] * 256 + d];
    const u16 h = f2h(v);
    P[gid] = h;
    if (d < 256) annf[((size_t)row << 8) + d] = h;
}

// Wio[n][k], n = dir*2048 + e*512 + h : = W_dir[e][k][h]
__global__ void s_wio(const float* __restrict__ Wi, const float* __restrict__ Wo,
                      u16* __restrict__ dst)
{
    const int gid = blockIdx.x * 256 + threadIdx.x;  // < 4096*512
    if (gid >= 4096 * 512) return;
    const int nn = gid >> 9, k = gid & 511;
    const int dir = nn >> 11, e = (nn >> 9) & 3, h = nn & 511;
    const float* W = dir ? Wo : Wi;
    dst[gid] = f2h(W[(size_t)e * 512 * 512 + (size_t)k * 512 + h]);
}

// Wrzh[n][k] (1536x1536): n<512 Wr[k][n]; n<1024 Wz[k][n-512]; else (k<1024 ? Wh[k][n-1024] : 0)
__global__ void s_wrzh(const float* __restrict__ Wr, const float* __restrict__ Wz,
                       const float* __restrict__ Wh, u16* __restrict__ dst)
{
    const int gid = blockIdx.x * 256 + threadIdx.x;  // < 1536*1536
    if (gid >= 1536 * 1536) return;
    const int nn = gid / 1536, k = gid - nn * 1536;
    float v;
    if (nn < 512)       v = Wr[(size_t)k * 512 + nn];
    else if (nn < 1024) v = Wz[(size_t)k * 512 + (nn - 512)];
    else                v = (k < 1024) ? Wh[(size_t)k * 512 + (nn - 1024)] : 0.0f;
    dst[gid] = f2h(v);
}

// WhP[n][k] (512x512): = Wh[1024+k][n]
__global__ void s_whp(const float* __restrict__ Wh, u16* __restrict__ dst)
{
    const int gid = blockIdx.x * 256 + threadIdx.x;  // < 512*512
    if (gid >= 512 * 512) return;
    const int nn = gid >> 9, k = gid & 511;
    dst[gid] = f2h(Wh[(size_t)(1024 + k) * 512 + nn]);
}

// Wj[n][k] (512x768): = Wo[k][n]
__global__ void s_wj(const float* __restrict__ Wo, u16* __restrict__ dst)
{
    const int gid = blockIdx.x * 256 + threadIdx.x;  // < 512*768
    if (gid >= 512 * 768) return;
    const int nn = gid / 768, k = gid - nn * 768;
    dst[gid] = f2h(Wo[(size_t)k * 512 + nn]);
}

extern "C" void kernel_launch(void* const* d_in, const int* in_sizes, int n_in,
                              void* d_out, int out_size, void* d_ws, size_t ws_size,
                              hipStream_t stream) {
    const int*   ann   = (const int*)d_in[0];
    const float* A     = (const float*)d_in[1];
    const float* emb   = (const float*)d_in[2];
    const float* W_in  = (const float*)d_in[3];
    const float* b_in  = (const float*)d_in[4];
    const float* W_out = (const float*)d_in[5];
    const float* b_out = (const float*)d_in[6];
    const float* Wr    = (const float*)d_in[7];
    const float* br    = (const float*)d_in[8];
    const float* Wz    = (const float*)d_in[9];
    const float* bz    = (const float*)d_in[10];
    const float* Wh    = (const float*)d_in[11];
    const float* bh    = (const float*)d_in[12];
    const float* Wo    = (const float*)d_in[13];
    const float* bo    = (const float*)d_in[14];
    float* out = (float*)d_out;

    char* ws = (char*)d_ws;
    size_t off = 0;
    auto alloc = [&](size_t bytes) -> void* {
        void* p = ws + off;
        off = (off + bytes + 255) & ~(size_t)255;
        return p;
    };
    float* z_f32 = (float*)alloc(8192ull * 512 * 4);   // 16 MB
    float* hpart = (float*)alloc(8192ull * 512 * 4);   // 16 MB
    u16* P     = (u16*)alloc(8192ull * 512 * 2);       // 8 MB
    u16* rp    = (u16*)alloc(8192ull * 512 * 2);       // 8 MB
    u16* annf  = (u16*)alloc(8192ull * 256 * 2);       // 4 MB
    u16* acat  = (u16*)alloc(8192ull * 1024 * 2);      // 16 MB
    u16* T     = (u16*)alloc(2 * TDIR * 2);            // 64 MB (both dirs)
    u16* WioT  = (u16*)alloc(4096ull * 512 * 2);       // 4 MB
    u16* WrzhT = (u16*)alloc(1536ull * 1536 * 2);      // 4.7 MB
    u16* WhPT  = (u16*)alloc(512ull * 512 * 2);        // 0.5 MB
    u16* WjT   = (u16*)alloc(512ull * 768 * 2);        // 0.8 MB
    // total ~142 MB

    s_gather<<<16384, 256, 0, stream>>>(ann, emb, P, annf);
    s_wio<<<(4096 * 512 + 255) / 256, 256, 0, stream>>>(W_in, W_out, WioT);
    s_wrzh<<<(1536 * 1536 + 255) / 256, 256, 0, stream>>>(Wr, Wz, Wh, WrzhT);
    s_whp<<<(512 * 512 + 255) / 256, 256, 0, stream>>>(Wh, WhPT);
    s_wj<<<(512 * 768 + 255) / 256, 256, 0, stream>>>(Wo, WjT);

    for (int s = 0; s < 5; ++s) {
        k_proj<<<2048, 256, 0, stream>>>(P, WioT, b_in, b_out, T);
        k_amat<<<512, 256, 0, stream>>>(A, T, acat);
        k_gates<<<768, 256, 0, stream>>>(acat, P, WrzhT, br, bz, rp, z_f32, hpart);
        k_hup<<<256, 256, 0, stream>>>(rp, WhPT, bh, z_f32, hpart, P);
    }
    k_final<<<256, 256, 0, stream>>>(P, annf, WjT, bo, out);
}

// Round 6
// 965.428 us; speedup vs baseline: 2.6739x; 1.0532x over previous
//
#include <hip/hip_runtime.h>
#include <hip/hip_bf16.h>
#include <cstdint>
#include <cstddef>

typedef unsigned short u16;
typedef _Float16 f16;
typedef f16 f16x8 __attribute__((ext_vector_type(8)));
typedef float f32x4 __attribute__((ext_vector_type(4)));

static __device__ inline u16 f2h(float f) {
    f16 h = (f16)f;
    return *reinterpret_cast<u16*>(&h);
}
static __device__ inline float h2f(u16 u) {
    f16 h = *reinterpret_cast<f16*>(&u);
    return (float)h;
}

// async global->LDS, 16B per lane; LDS dest = wave-uniform base + lane*16
#define GLL(g, l) __builtin_amdgcn_global_load_lds(                    \
    (const __attribute__((address_space(1))) void*)(g),                \
    (__attribute__((address_space(3))) void*)(l), 16, 0, 0)

// bijective XCD swizzle (all grids % 8 == 0)
static __device__ inline int xcd_swz(int fid, int nwg) {
    const int q = nwg >> 3;
    return (fid & 7) * q + (fid >> 3);
}

// stage a 128x32 u16 tile (row-major src, ld elements) into linear lds[128*32]
static __device__ inline void stage_tile(const u16* __restrict__ src, int ld,
                                         u16* lds, int wave, int lane) {
    const int r = lane >> 2;
    const int c = (lane & 3) << 3;
    const u16* g0 = src + (size_t)(wave * 32 + r) * ld + c;
    GLL(g0, lds + wave * 1024);
    GLL(g0 + (size_t)16 * ld, lds + wave * 1024 + 512);
}

// one K=32 step: wave computes its 64x64 quadrant = 4x4 16x16x32 MFMAs
static __device__ inline void compute32(const u16* lA, const u16* lB,
                                        int wq_r, int wq_c, int lr, int lk,
                                        f32x4 acc[4][4]) {
    f16x8 a[4], b[4];
    #pragma unroll
    for (int i = 0; i < 4; ++i)
        a[i] = *reinterpret_cast<const f16x8*>(&lA[(wq_r + i * 16 + lr) * 32 + lk]);
    #pragma unroll
    for (int j = 0; j < 4; ++j)
        b[j] = *reinterpret_cast<const f16x8*>(&lB[(wq_c + j * 16 + lr) * 32 + lk]);
    #pragma unroll
    for (int i = 0; i < 4; ++i)
        #pragma unroll
        for (int j = 0; j < 4; ++j)
            acc[i][j] = __builtin_amdgcn_mfma_f32_16x16x32_f16(a[i], b[j], acc[i][j], 0, 0, 0);
}

// C[128x128] = concat(a1,a2)[M x K] @ bt[N x K]^T ; u16(f16) sources, dbuf 2-phase
static __device__ inline void gemm128(const u16* __restrict__ a1, int lda1, int ka1,
                                      const u16* __restrict__ a2, int lda2,
                                      const u16* __restrict__ bt, int ldb,
                                      int K, int m0, int n0,
                                      u16* sA, u16* sB, f32x4 acc[4][4])
{
    const int t = threadIdx.x, lane = t & 63, wave = t >> 6;
    const int lr = lane & 15, lk = (lane >> 4) << 3;
    const int wq_r = (wave >> 1) << 6, wq_c = (wave & 1) << 6;
    const int nt = K >> 5;
    stage_tile(a1 + (size_t)m0 * lda1, lda1, sA, wave, lane);
    stage_tile(bt + (size_t)n0 * ldb, ldb, sB, wave, lane);
    __syncthreads();
    int buf = 0;
    for (int ti = 0; ti < nt; ++ti) {
        const int k1 = (ti + 1) << 5;
        if (k1 < K) {
            const u16* s;
            int ld;
            if (k1 < ka1) { s = a1 + (size_t)m0 * lda1 + k1;        ld = lda1; }
            else          { s = a2 + (size_t)m0 * lda2 + (k1 - ka1); ld = lda2; }
            stage_tile(s, ld, sA + (buf ^ 1) * 4096, wave, lane);
            stage_tile(bt + (size_t)n0 * ldb + k1, ldb, sB + (buf ^ 1) * 4096, wave, lane);
        }
        compute32(sA + buf * 4096, sB + buf * 4096, wq_r, wq_c, lr, lk, acc);
        __syncthreads();
        buf ^= 1;
    }
}

#define EPI                                         \
    const int lane = threadIdx.x & 63;              \
    const int wave = threadIdx.x >> 6;              \
    const int wq_r = (wave >> 1) << 6;              \
    const int wq_c = (wave & 1) << 6;               \
    const int lr = lane & 15;                       \
    const int l4 = (lane >> 4) << 2;

#define TDIR (32ull * 512 * 1024)

// mega-projection: C[8192 x 4096] = P @ WioT^T ; col = dir*2048 + e*512 + h
// write transposed: T[dir][b][h][e*256+m]
__global__ __launch_bounds__(256, 4) void k_proj(const u16* __restrict__ P,
                                                 const u16* __restrict__ Wio,
                                                 const float* __restrict__ b_in,
                                                 const float* __restrict__ b_out,
                                                 u16* __restrict__ T)
{
    __shared__ u16 sA[2 * 4096], sB[2 * 4096];
    const int fid = xcd_swz(blockIdx.x, gridDim.x);
    const int n = fid & 31, m = fid >> 5;
    const int m0 = m << 7, n0 = n << 7;
    f32x4 acc[4][4] = {};
    gemm128(P, 512, 512, P, 512, Wio, 512, 512, m0, n0, sA, sB, acc);
    EPI
    #pragma unroll
    for (int i = 0; i < 4; ++i) {
        const int row = m0 + wq_r + i * 16 + l4;
        const int b = row >> 8, mm = row & 255;
        #pragma unroll
        for (int j = 0; j < 4; ++j) {
            const int col = n0 + wq_c + j * 16 + lr;
            const int dir = col >> 11, eh = col & 2047;
            const float bia = (dir ? b_out : b_in)[eh];
            const int e = eh >> 9, h = eh & 511;
            ushort4 w4;
            w4.x = f2h(acc[i][j][0] + bia);
            w4.y = f2h(acc[i][j][1] + bia);
            w4.z = f2h(acc[i][j][2] + bia);
            w4.w = f2h(acc[i][j][3] + bia);
            u16* dst = T + (size_t)dir * TDIR + (size_t)b * 512 * 1024 + (size_t)h * 1024 + e * 256 + mm;
            *reinterpret_cast<ushort4*>(dst) = w4;
        }
    }
}

// adjacency: per (b,dir): C = A16[b][:, dir*1024:+1024] @ T[dir][b]^T -> acat cols dir*512..+512
__global__ __launch_bounds__(256, 4) void k_amat(const u16* __restrict__ A16,
                                                 const u16* __restrict__ T,
                                                 u16* __restrict__ acat)
{
    __shared__ u16 sA[2 * 4096], sB[2 * 4096];
    const int fid = xcd_swz(blockIdx.x, gridDim.x);
    const int n = fid & 3, m = (fid >> 2) & 1, bd = fid >> 3;
    const int b = bd >> 1, dir = bd & 1;
    const int m0 = m << 7, n0 = n << 7;
    const u16* A1 = A16 + (size_t)b * 256 * 2048 + dir * 1024;
    const u16* Bt = T + (size_t)dir * TDIR + (size_t)b * 512 * 1024;
    f32x4 acc[4][4] = {};
    gemm128(A1, 2048, 1024, A1, 2048, Bt, 1024, 1024, m0, n0, sA, sB, acc);
    EPI
    #pragma unroll
    for (int i = 0; i < 4; ++i) {
        const int row = m0 + wq_r + i * 16 + l4;
        #pragma unroll
        for (int j = 0; j < 4; ++j) {
            const int col = n0 + wq_c + j * 16 + lr;
            #pragma unroll
            for (int v = 0; v < 4; ++v)
                acat[((size_t)b * 256 + row + v) * 1024 + dir * 512 + col] = f2h(acc[i][j][v]);
        }
    }
}

// gates: X[8192 x 1536] = [acat | P] @ Wrzh^T  (Wrzh h-block zero-padded over P rows)
// n<512: rp = f16(sigmoid(X+br)*P) ; n<1024: z = sigmoid(X+bz) ; else hpart = X (f32, no bias)
__global__ __launch_bounds__(256, 4) void k_gates(const u16* __restrict__ acat,
                                                  const u16* __restrict__ P,
                                                  const u16* __restrict__ Wrzh,
                                                  const float* __restrict__ br,
                                                  const float* __restrict__ bz,
                                                  u16* __restrict__ rp,
                                                  float* __restrict__ z,
                                                  float* __restrict__ hpart)
{
    __shared__ u16 sA[2 * 4096], sB[2 * 4096];
    const int fid = xcd_swz(blockIdx.x, gridDim.x);
    const int n = fid % 12, m = fid / 12;
    const int m0 = m << 7, n0 = n << 7;
    f32x4 acc[4][4] = {};
    gemm128(acat, 1024, 1024, P, 512, Wrzh, 1536, 1536, m0, n0, sA, sB, acc);
    EPI
    #pragma unroll
    for (int i = 0; i < 4; ++i) {
        const int row = m0 + wq_r + i * 16 + l4;
        #pragma unroll
        for (int j = 0; j < 4; ++j) {
            const int col = n0 + wq_c + j * 16 + lr;
            if (col < 512) {
                const float bia = br[col];
                #pragma unroll
                for (int v = 0; v < 4; ++v) {
                    const float s = 1.0f / (1.0f + __expf(-(acc[i][j][v] + bia)));
                    const size_t idx = (size_t)(row + v) * 512 + col;
                    rp[idx] = f2h(s * h2f(P[idx]));
                }
            } else if (col < 1024) {
                const float bia = bz[col - 512];
                #pragma unroll
                for (int v = 0; v < 4; ++v)
                    z[(size_t)(row + v) * 512 + (col - 512)] =
                        1.0f / (1.0f + __expf(-(acc[i][j][v] + bia)));
            } else {
                #pragma unroll
                for (int v = 0; v < 4; ++v)
                    hpart[(size_t)(row + v) * 512 + (col - 1024)] = acc[i][j][v];
            }
        }
    }
}

// h/update: Y = rp @ WhP^T (K=512) ; h = tanh(hpart + Y + bh) ; P = (1-z)P + z h
__global__ __launch_bounds__(256, 4) void k_hup(const u16* __restrict__ rp,
                                                const u16* __restrict__ WhP,
                                                const float* __restrict__ bh,
                                                const float* __restrict__ z,
                                                const float* __restrict__ hpart,
                                                u16* __restrict__ P)
{
    __shared__ u16 sA[2 * 4096], sB[2 * 4096];
    const int fid = xcd_swz(blockIdx.x, gridDim.x);
    const int n = fid & 3, m = fid >> 2;
    const int m0 = m << 7, n0 = n << 7;
    f32x4 acc[4][4] = {};
    gemm128(rp, 512, 512, rp, 512, WhP, 512, 512, m0, n0, sA, sB, acc);
    EPI
    #pragma unroll
    for (int i = 0; i < 4; ++i) {
        const int row = m0 + wq_r + i * 16 + l4;
        #pragma unroll
        for (int j = 0; j < 4; ++j) {
            const int col = n0 + wq_c + j * 16 + lr;
            const float bia = bh[col];
            #pragma unroll
            for (int v = 0; v < 4; ++v) {
                const size_t idx = (size_t)(row + v) * 512 + col;
                const float hh = tanhf(hpart[idx] + acc[i][j][v] + bia);
                const float zz = z[idx];
                const float pn = (1.0f - zz) * h2f(P[idx]) + zz * hh;
                P[idx] = f2h(pn);
            }
        }
    }
}

// final: out = tanh([P | ann] @ Wj^T + bo) (f32)
__global__ __launch_bounds__(256, 4) void k_final(const u16* __restrict__ P,
                                                  const u16* __restrict__ annf,
                                                  const u16* __restrict__ Wj,
                                                  const float* __restrict__ bo,
                                                  float* __restrict__ out)
{
    __shared__ u16 sA[2 * 4096], sB[2 * 4096];
    const int fid = xcd_swz(blockIdx.x, gridDim.x);
    const int n = fid & 3, m = fid >> 2;
    const int m0 = m << 7, n0 = n << 7;
    f32x4 acc[4][4] = {};
    gemm128(P, 512, 512, annf, 256, Wj, 768, 768, m0, n0, sA, sB, acc);
    EPI
    #pragma unroll
    for (int i = 0; i < 4; ++i) {
        const int row = m0 + wq_r + i * 16 + l4;
        #pragma unroll
        for (int j = 0; j < 4; ++j) {
            const int col = n0 + wq_c + j * 16 + lr;
            const float bia = bo[col];
            #pragma unroll
            for (int v = 0; v < 4; ++v)
                out[(size_t)(row + v) * 512 + col] = tanhf(acc[i][j][v] + bia);
        }
    }
}

// ---- setup ----
__global__ void s_gather(const int* __restrict__ ann, const float* __restrict__ emb,
                         u16* __restrict__ P, u16* __restrict__ annf)
{
    const int gid = blockIdx.x * 256 + threadIdx.x;  // < 8192*512
    const int row = gid >> 9, d = gid & 511;
    float v = 0.0f;
    if (d < 256) v = emb[(size_t)ann[row] * 256 + d];
    const u16 h = f2h(v);
    P[gid] = h;
    if (d < 256) annf[((size_t)row << 8) + d] = h;
}

// A f32 -> f16, 8 elems/thread
__global__ void s_cvtA(const float* __restrict__ src, u16* __restrict__ dst)
{
    const size_t base = ((size_t)blockIdx.x * 256 + threadIdx.x) * 8;  // < 8192*2048
    float4 f0 = *reinterpret_cast<const float4*>(src + base);
    float4 f1 = *reinterpret_cast<const float4*>(src + base + 4);
    ushort4 p0 = { f2h(f0.x), f2h(f0.y), f2h(f0.z), f2h(f0.w) };
    ushort4 p1 = { f2h(f1.x), f2h(f1.y), f2h(f1.z), f2h(f1.w) };
    *reinterpret_cast<ushort4*>(dst + base)     = p0;
    *reinterpret_cast<ushort4*>(dst + base + 4) = p1;
}

// Wio[n][k], n = dir*2048 + e*512 + h : = W_dir[e][k][h]
__global__ void s_wio(const float* __restrict__ Wi, const float* __restrict__ Wo,
                      u16* __restrict__ dst)
{
    const int gid = blockIdx.x * 256 + threadIdx.x;  // < 4096*512
    if (gid >= 4096 * 512) return;
    const int nn = gid >> 9, k = gid & 511;
    const int dir = nn >> 11, e = (nn >> 9) & 3, h = nn & 511;
    const float* W = dir ? Wo : Wi;
    dst[gid] = f2h(W[(size_t)e * 512 * 512 + (size_t)k * 512 + h]);
}

// Wrzh[n][k] (1536x1536): n<512 Wr[k][n]; n<1024 Wz[k][n-512]; else (k<1024 ? Wh[k][n-1024] : 0)
__global__ void s_wrzh(const float* __restrict__ Wr, const float* __restrict__ Wz,
                       const float* __restrict__ Wh, u16* __restrict__ dst)
{
    const int gid = blockIdx.x * 256 + threadIdx.x;  // < 1536*1536
    if (gid >= 1536 * 1536) return;
    const int nn = gid / 1536, k = gid - nn * 1536;
    float v;
    if (nn < 512)       v = Wr[(size_t)k * 512 + nn];
    else if (nn < 1024) v = Wz[(size_t)k * 512 + (nn - 512)];
    else                v = (k < 1024) ? Wh[(size_t)k * 512 + (nn - 1024)] : 0.0f;
    dst[gid] = f2h(v);
}

// WhP[n][k] (512x512): = Wh[1024+k][n]
__global__ void s_whp(const float* __restrict__ Wh, u16* __restrict__ dst)
{
    const int gid = blockIdx.x * 256 + threadIdx.x;  // < 512*512
    if (gid >= 512 * 512) return;
    const int nn = gid >> 9, k = gid & 511;
    dst[gid] = f2h(Wh[(size_t)(1024 + k) * 512 + nn]);
}

// Wj[n][k] (512x768): = Wo[k][n]
__global__ void s_wj(const float* __restrict__ Wo, u16* __restrict__ dst)
{
    const int gid = blockIdx.x * 256 + threadIdx.x;  // < 512*768
    if (gid >= 512 * 768) return;
    const int nn = gid / 768, k = gid - nn * 768;
    dst[gid] = f2h(Wo[(size_t)k * 512 + nn]);
}

extern "C" void kernel_launch(void* const* d_in, const int* in_sizes, int n_in,
                              void* d_out, int out_size, void* d_ws, size_t ws_size,
                              hipStream_t stream) {
    const int*   ann   = (const int*)d_in[0];
    const float* A     = (const float*)d_in[1];
    const float* emb   = (const float*)d_in[2];
    const float* W_in  = (const float*)d_in[3];
    const float* b_in  = (const float*)d_in[4];
    const float* W_out = (const float*)d_in[5];
    const float* b_out = (const float*)d_in[6];
    const float* Wr    = (const float*)d_in[7];
    const float* br    = (const float*)d_in[8];
    const float* Wz    = (const float*)d_in[9];
    const float* bz    = (const float*)d_in[10];
    const float* Wh    = (const float*)d_in[11];
    const float* bh    = (const float*)d_in[12];
    const float* Wo    = (const float*)d_in[13];
    const float* bo    = (const float*)d_in[14];
    float* out = (float*)d_out;

    char* ws = (char*)d_ws;
    size_t off = 0;
    auto alloc = [&](size_t bytes) -> void* {
        void* p = ws + off;
        off = (off + bytes + 255) & ~(size_t)255;
        return p;
    };
    float* z_f32 = (float*)alloc(8192ull * 512 * 4);   // 16 MB
    float* hpart = (float*)alloc(8192ull * 512 * 4);   // 16 MB
    u16* P     = (u16*)alloc(8192ull * 512 * 2);       // 8 MB
    u16* rp    = (u16*)alloc(8192ull * 512 * 2);       // 8 MB
    u16* annf  = (u16*)alloc(8192ull * 256 * 2);       // 4 MB
    u16* acat  = (u16*)alloc(8192ull * 1024 * 2);      // 16 MB
    u16* A16   = (u16*)alloc(8192ull * 2048 * 2);      // 32 MB
    u16* T     = (u16*)alloc(2 * TDIR * 2);            // 64 MB (both dirs)
    u16* WioT  = (u16*)alloc(4096ull * 512 * 2);       // 4 MB
    u16* WrzhT = (u16*)alloc(1536ull * 1536 * 2);      // 4.7 MB
    u16* WhPT  = (u16*)alloc(512ull * 512 * 2);        // 0.5 MB
    u16* WjT   = (u16*)alloc(512ull * 768 * 2);        // 0.8 MB
    // total ~174 MB

    s_gather<<<16384, 256, 0, stream>>>(ann, emb, P, annf);
    s_cvtA<<<8192, 256, 0, stream>>>(A, A16);
    s_wio<<<(4096 * 512 + 255) / 256, 256, 0, stream>>>(W_in, W_out, WioT);
    s_wrzh<<<(1536 * 1536 + 255) / 256, 256, 0, stream>>>(Wr, Wz, Wh, WrzhT);
    s_whp<<<(512 * 512 + 255) / 256, 256, 0, stream>>>(Wh, WhPT);
    s_wj<<<(512 * 768 + 255) / 256, 256, 0, stream>>>(Wo, WjT);

    for (int s = 0; s < 5; ++s) {
        k_proj<<<2048, 256, 0, stream>>>(P, WioT, b_in, b_out, T);
        k_amat<<<512, 256, 0, stream>>>(A16, T, acat);
        k_gates<<<768, 256, 0, stream>>>(acat, P, WrzhT, br, bz, rp, z_f32, hpart);
        k_hup<<<256, 256, 0, stream>>>(rp, WhPT, bh, z_f32, hpart, P);
    }
    k_final<<<256, 256, 0, stream>>>(P, annf, WjT, bo, out);
}